// Round 5
// baseline (2753.864 us; speedup 1.0000x reference)
//
#include <hip/hip_runtime.h>
#include <hip/hip_bf16.h>

// ShiftWindAttention on MI355X (gfx950), bf16 MFMA pipeline.
// Round 5: 256x256 tile, BK=32 double-buffered (LDS 64KiB -> 2 blocks/CU),
// 2 phases/K-tile, counted vmcnt(2), row-XOR swizzle for 64B rows.

typedef __attribute__((ext_vector_type(4))) float f32x4;
typedef __attribute__((ext_vector_type(8))) __bf16 bf16x8;
typedef __attribute__((ext_vector_type(8))) unsigned short u16x8;

__device__ __forceinline__ unsigned short f2bf(float f) {
  __hip_bfloat16 h = __float2bfloat16(f);
  return __builtin_bit_cast(unsigned short, h);
}
__device__ __forceinline__ float bf2f(unsigned short u) {
  return __builtin_bit_cast(float, ((unsigned int)u) << 16);
}

#define GLL16(gsrc, ldst)                                                              \
  __builtin_amdgcn_global_load_lds((const __attribute__((address_space(1))) void*)(gsrc), \
                                   (__attribute__((address_space(3))) void*)(ldst), 16, 0, 0)

// Row-XOR swizzle for 64B rows (involution): toggle 16B-slot bits [5:4] with row bits [8:7].
// Preserves bits 0-3 (16B chunks stay contiguous) and the row (bits >=6).
#define SWZ(x) ((x) ^ ((((x) >> 7) & 3) << 4))

#define MFMA_BF16 __builtin_amdgcn_mfma_f32_16x16x32_bf16

// ---------------- conversion kernels ----------------
__global__ __launch_bounds__(256) void cvt_x_kernel(const float* __restrict__ in,
                                                    unsigned short* __restrict__ out, int n4) {
  int i = blockIdx.x * blockDim.x + threadIdx.x;
  int stride = gridDim.x * blockDim.x;
  for (; i < n4; i += stride) {
    float4 v = reinterpret_cast<const float4*>(in)[i];
    ushort4 o;
    o.x = f2bf(v.x); o.y = f2bf(v.y); o.z = f2bf(v.z); o.w = f2bf(v.w);
    reinterpret_cast<ushort4*>(out)[i] = o;
  }
}

__global__ __launch_bounds__(256) void cvt_T_kernel(const float* __restrict__ in,
                                                    unsigned short* __restrict__ out,
                                                    int R, int C) {
  int idx = blockIdx.x * 256 + threadIdx.x;
  if (idx < R * C) {
    int r = idx / C, c = idx - r * C;
    out[(size_t)c * R + r] = f2bf(in[idx]);
  }
}

// ---------------- 256x256 GEMM, BK=32 dbuf: C[M,N] = A[M,K] * B[N,K]^T ----------------
// 512 threads = 8 waves (2M x 4N), per-wave 128x64 out. LDS 64KiB -> 2 blocks/CU.
// Per K-tile u: ph1 {read A m0-3 + B all; stage A(u+1); MFMA m0-3}
//               ph2 {read A m4-7; stage B(u+2); vmcnt(2); MFMA m4-7}
template <bool OUT_BF16>
__global__ __launch_bounds__(512, 4) void gemm2p(const unsigned short* __restrict__ A, int lda,
                                                 const unsigned short* __restrict__ B, int ldb,
                                                 void* __restrict__ Cv, int ldc,
                                                 const float* __restrict__ bias, int N, int K) {
  __shared__ alignas(16) unsigned char lds[65536];  // A: [0,32K) 2x16K; B: [32K,64K) 2x16K
  const int tid = threadIdx.x, lane = tid & 63, wave = tid >> 6;
  const int wm = wave >> 2, wn = wave & 3;
  const int nbn = N >> 8;
  const int nwg = gridDim.x;
  const int b0 = blockIdx.x;
  const int sb = (b0 & 7) * (nwg >> 3) + (b0 >> 3);  // bijective: nwg % 8 == 0
  const int bm = sb / nbn, bn = sb - bm * nbn;
  const int m0 = bm << 8, n0 = bn << 8;
  const int nkt = K >> 5;

  // staging: tile = 256 rows x 64B; thread covers bytes d0 (rows 0..127) and d0+8192.
  const int d0 = wave * 1024 + lane * 16;
  const int r0g = d0 >> 6;                 // 0..127
  const int c0 = (SWZ(d0) & 63) >> 1;      // elem col (16B-aligned), inverse-swizzled source
  const int d1 = d0 + 8192;
  const int r1g = d1 >> 6;                 // 128..255
  const int c1 = (SWZ(d1) & 63) >> 1;

  const int fr = lane & 15, fk = lane >> 4;
  const int fkb = fk * 16;                 // 16B k-slot within 64B row

  auto STAGE = [&](const unsigned short* __restrict__ S, int ld, int rbase, int kt, int base) {
    const unsigned short* s0 = S + (size_t)(rbase + r0g) * ld + kt * 32 + c0;
    const unsigned short* s1 = S + (size_t)(rbase + r1g) * ld + kt * 32 + c1;
    auto* lb = &lds[base + wave * 1024];  // wave-uniform dest
    GLL16(s0, lb);
    GLL16(s1, lb + 8192);
  };
  auto LDA_ = [&](int abuf, int mi) -> bf16x8 {
    const int e = (wm * 128 + mi * 16 + fr) * 64 + fkb;
    return *reinterpret_cast<const bf16x8*>(&lds[abuf + SWZ(e)]);
  };
  auto LDB_ = [&](int bbuf, int ni) -> bf16x8 {
    const int e = (wn * 64 + ni * 16 + fr) * 64 + fkb;
    return *reinterpret_cast<const bf16x8*>(&lds[bbuf + SWZ(e)]);
  };

  // prologue: A(0), B(0), B(1); vmcnt(2) leaves B(1) in flight
  STAGE(A, lda, m0, 0, 0);
  STAGE(B, ldb, n0, 0, 32768);
  STAGE(B, ldb, n0, (nkt > 1) ? 1 : 0, 32768 + 16384);
  asm volatile("s_waitcnt vmcnt(2)" ::: "memory");
  __builtin_amdgcn_s_barrier();

  f32x4 acc[8][4] = {};
  bf16x8 Af[4], Bf[4];

  for (int u = 0; u < nkt; ++u) {
    const int abuf = (u & 1) * 16384;
    const int anx = ((u + 1) & 1) * 16384;
    const int bbuf = 32768 + (u & 1) * 16384;
    const int kA = (u + 1 < nkt) ? u + 1 : nkt - 1;
    const int kB = (u + 2 < nkt) ? u + 2 : nkt - 1;

    // ---- phase 1: read A m0-3 + B n0-3; stage A(u+1); MFMA (m0-3 x n0-3)
#pragma unroll
    for (int mi = 0; mi < 4; ++mi) Af[mi] = LDA_(abuf, mi);
#pragma unroll
    for (int ni = 0; ni < 4; ++ni) Bf[ni] = LDB_(bbuf, ni);
    STAGE(A, lda, m0, kA, anx);
    __builtin_amdgcn_s_barrier();
    asm volatile("s_waitcnt lgkmcnt(0)" ::: "memory");
    __builtin_amdgcn_s_setprio(1);
#pragma unroll
    for (int mi = 0; mi < 4; ++mi)
#pragma unroll
      for (int ni = 0; ni < 4; ++ni)
        acc[mi][ni] = MFMA_BF16(Af[mi], Bf[ni], acc[mi][ni], 0, 0, 0);
    __builtin_amdgcn_s_setprio(0);
    __builtin_amdgcn_s_barrier();

    // ---- phase 2: read A m4-7; stage B(u+2) into bbuf (reads done in ph1); vmcnt(2)
#pragma unroll
    for (int mi = 0; mi < 4; ++mi) Af[mi] = LDA_(abuf, 4 + mi);
    STAGE(B, ldb, n0, kB, bbuf);
    asm volatile("s_waitcnt vmcnt(2)" ::: "memory");
    __builtin_amdgcn_s_barrier();
    asm volatile("s_waitcnt lgkmcnt(0)" ::: "memory");
    __builtin_amdgcn_s_setprio(1);
#pragma unroll
    for (int mi = 0; mi < 4; ++mi)
#pragma unroll
      for (int ni = 0; ni < 4; ++ni)
        acc[4 + mi][ni] = MFMA_BF16(Af[mi], Bf[ni], acc[4 + mi][ni], 0, 0, 0);
    __builtin_amdgcn_s_setprio(0);
    __builtin_amdgcn_s_barrier();
  }

  // epilogue: C/D layout col = lane&15, row = (lane>>4)*4 + r
  const int er = fk << 2;
#pragma unroll
  for (int mi = 0; mi < 8; ++mi)
#pragma unroll
    for (int ni = 0; ni < 4; ++ni) {
      const int col = n0 + wn * 64 + ni * 16 + fr;
#pragma unroll
      for (int r = 0; r < 4; ++r) {
        const size_t row = (size_t)(m0 + wm * 128 + mi * 16 + er + r);
        if (OUT_BF16)
          ((unsigned short*)Cv)[row * ldc + col] = f2bf(acc[mi][ni][r]);
        else
          ((float*)Cv)[row * ldc + col] = acc[mi][ni][r] + bias[col];
      }
    }
}

// ---------------- windowed attention ----------------
__device__ __forceinline__ int region_of(int wy, int wx, int t) {
  int yr = wy * 8 + (t >> 3);
  int xr = wx * 8 + (t & 7);
  int ry = (yr < 24) ? 0 : ((yr < 28) ? 1 : 2);
  int rx = (xr < 24) ? 0 : ((xr < 28) ? 1 : 2);
  return ry * 3 + rx;
}

__global__ __launch_bounds__(256) void win_attn(const unsigned short* __restrict__ qkv,
                                                const float* __restrict__ bias_table,
                                                unsigned short* __restrict__ out,
                                                int nb16) {
  __shared__ alignas(16) unsigned short vt[4][64][72];
  __shared__ alignas(16) unsigned short pl[4][64][72];
  __shared__ unsigned short bias_sh[225 * 16];

  const int tid = threadIdx.x, lane = tid & 63, wave = tid >> 6;
  const int bid = blockIdx.x;
  const int g = bid / nb16;
  const int bw = bid - g * nb16;
  const int b = bw >> 4, w = bw & 15;
  const int wy = w >> 2, wx = w & 3;
  const int shift = g ? 4 : 0;

  for (int i = tid; i < 225 * 16; i += 256) bias_sh[i] = f2bf(bias_table[i]);
  __syncthreads();

  const int r0 = lane & 15, hi4 = lane >> 4;

  for (int hh = 0; hh < 2; ++hh) {
    const int head = g * 8 + wave * 2 + hh;
    const int qcol = head * 64;

    bf16x8 qf[4][2], kf[4][2];
#pragma unroll
    for (int mi = 0; mi < 4; ++mi) {
      const int t = mi * 16 + r0;
      const int y = (wy * 8 + (t >> 3) + shift) & 31;
      const int x = (wx * 8 + (t & 7) + shift) & 31;
      const size_t base = (size_t)((b << 10) + (y << 5) + x) * 3072 + qcol;
#pragma unroll
      for (int kb = 0; kb < 2; ++kb) {
        const int d = kb * 32 + hi4 * 8;
        qf[mi][kb] = *reinterpret_cast<const bf16x8*>(&qkv[base + d]);
        kf[mi][kb] = *reinterpret_cast<const bf16x8*>(&qkv[base + 1024 + d]);
      }
    }

    {
      const int y = (wy * 8 + (lane >> 3) + shift) & 31;
      const int x = (wx * 8 + (lane & 7) + shift) & 31;
      const unsigned short* vsrc =
          qkv + (size_t)((b << 10) + (y << 5) + x) * 3072 + 2048 + qcol;
#pragma unroll
      for (int d0 = 0; d0 < 8; ++d0) {
        u16x8 vv = *reinterpret_cast<const u16x8*>(&vsrc[d0 * 8]);
#pragma unroll
        for (int jj = 0; jj < 8; ++jj) vt[wave][d0 * 8 + jj][lane] = vv[jj];
      }
    }

    f32x4 s[4][4] = {};
#pragma unroll
    for (int mi = 0; mi < 4; ++mi)
#pragma unroll
      for (int ni = 0; ni < 4; ++ni) {
        s[mi][ni] = MFMA_BF16(qf[mi][0], kf[ni][0], s[mi][ni], 0, 0, 0);
        s[mi][ni] = MFMA_BF16(qf[mi][1], kf[ni][1], s[mi][ni], 0, 0, 0);
      }

    int rj[4];
#pragma unroll
    for (int ni = 0; ni < 4; ++ni) rj[ni] = region_of(wy, wx, ni * 16 + r0);
    float rinv[4][4];
#pragma unroll
    for (int mi = 0; mi < 4; ++mi) {
#pragma unroll
      for (int r = 0; r < 4; ++r) {
        const int it = mi * 16 + hi4 * 4 + r;
        const int iy = it >> 3, ix = it & 7;
        const int ri = region_of(wy, wx, it);
        float vals[4], vmax = -1e30f;
#pragma unroll
        for (int ni = 0; ni < 4; ++ni) {
          const int jt = ni * 16 + r0;
          const int ridx = (iy - (jt >> 3) + 7) * 15 + (ix - (jt & 7) + 7);
          float v = s[mi][ni][r] * 0.125f + bf2f(bias_sh[ridx * 16 + head]);
          if (g && ri != rj[ni]) v = -1e9f;
          vals[ni] = v;
          vmax = fmaxf(vmax, v);
        }
        vmax = fmaxf(vmax, __shfl_xor(vmax, 1));
        vmax = fmaxf(vmax, __shfl_xor(vmax, 2));
        vmax = fmaxf(vmax, __shfl_xor(vmax, 4));
        vmax = fmaxf(vmax, __shfl_xor(vmax, 8));
        float ssum = 0.f;
#pragma unroll
        for (int ni = 0; ni < 4; ++ni) {
          float p = __expf(vals[ni] - vmax);
          ssum += p;
          s[mi][ni][r] = p;
        }
        ssum += __shfl_xor(ssum, 1);
        ssum += __shfl_xor(ssum, 2);
        ssum += __shfl_xor(ssum, 4);
        ssum += __shfl_xor(ssum, 8);
        rinv[mi][r] = 1.0f / ssum;
      }
    }

#pragma unroll
    for (int mi = 0; mi < 4; ++mi)
#pragma unroll
      for (int ni = 0; ni < 4; ++ni)
#pragma unroll
        for (int r = 0; r < 4; ++r)
          pl[wave][mi * 16 + hi4 * 4 + r][ni * 16 + r0] = f2bf(s[mi][ni][r]);

    f32x4 o[4][4] = {};
#pragma unroll
    for (int kb = 0; kb < 2; ++kb) {
      bf16x8 pf[4], vf[4];
#pragma unroll
      for (int mi = 0; mi < 4; ++mi)
        pf[mi] = *reinterpret_cast<const bf16x8*>(&pl[wave][mi * 16 + r0][kb * 32 + hi4 * 8]);
#pragma unroll
      for (int di = 0; di < 4; ++di)
        vf[di] = *reinterpret_cast<const bf16x8*>(&vt[wave][di * 16 + r0][kb * 32 + hi4 * 8]);
#pragma unroll
      for (int mi = 0; mi < 4; ++mi)
#pragma unroll
        for (int di = 0; di < 4; ++di)
          o[mi][di] = MFMA_BF16(pf[mi], vf[di], o[mi][di], 0, 0, 0);
    }

#pragma unroll
    for (int mi = 0; mi < 4; ++mi)
#pragma unroll
      for (int r = 0; r < 4; ++r) {
        const int it = mi * 16 + hi4 * 4 + r;
        const int y = (wy * 8 + (it >> 3) + shift) & 31;
        const int x = (wx * 8 + (it & 7) + shift) & 31;
        unsigned short* op = out + (size_t)((b << 10) + (y << 5) + x) * 3072 + head * 64;
        const float rv = rinv[mi][r];
#pragma unroll
        for (int di = 0; di < 4; ++di) op[di * 16 + r0] = f2bf(o[mi][di][r] * rv);
      }
  }
}

// ---------------- launcher ----------------
extern "C" void kernel_launch(void* const* d_in, const int* in_sizes, int n_in,
                              void* d_out, int out_size, void* d_ws, size_t ws_size,
                              hipStream_t stream) {
  const float* x = (const float*)d_in[0];
  const float* w_qkv = (const float*)d_in[1];
  const float* bias_table = (const float*)d_in[2];
  const float* w_out = (const float*)d_in[3];
  const float* b_out = (const float*)d_in[4];
  float* out = (float*)d_out;

  int S = 1;
  for (; S < 16; S <<= 1) {
    size_t need = 2ull * (2097152ull + 234881024ull / (size_t)S);
    if (need <= ws_size) break;
  }
  const int Mc = 65536 / S;
  const int nb = 64 / S;

  unsigned short* wqt = (unsigned short*)d_ws;
  unsigned short* wot = wqt + (size_t)1572864;
  unsigned short* xb  = wot + (size_t)524288;
  unsigned short* qkv = xb + (size_t)Mc * 512;

  cvt_T_kernel<<<6144, 256, 0, stream>>>(w_qkv, wqt, 512, 3072);
  cvt_T_kernel<<<2048, 256, 0, stream>>>(w_out, wot, 1024, 512);

  for (int c = 0; c < S; ++c) {
    const float* xc = x + (size_t)c * Mc * 512;
    cvt_x_kernel<<<2048, 256, 0, stream>>>(xc, xb, Mc * 128);
    gemm2p<true><<<(Mc >> 8) * 12, 512, 0, stream>>>(xb, 512, wqt, 512, (void*)qkv, 3072,
                                                     nullptr, 3072, 512);
    win_attn<<<2 * nb * 16, 256, 0, stream>>>(qkv, bias_table, qkv, nb * 16);
    gemm2p<false><<<(Mc >> 8) * 2, 512, 0, stream>>>(qkv, 3072, wot, 1024,
                                                     (void*)(out + (size_t)c * Mc * 512), 512,
                                                     b_out, 512, 1024);
  }
}

// Round 6
// 602.291 us; speedup vs baseline: 4.5723x; 4.5723x over previous
//
#include <hip/hip_runtime.h>
#include <hip/hip_bf16.h>

// ShiftWindAttention on MI355X (gfx950), bf16 MFMA pipeline.
// Round 6: 128x256 tile, BK=32 dbuf, 2 phases/K-tile, counted vmcnt(2),
// per-wave 64x64 (acc=64 regs -> no spill at 4 waves/SIMD, 2 blocks/CU).

typedef __attribute__((ext_vector_type(4))) float f32x4;
typedef __attribute__((ext_vector_type(8))) __bf16 bf16x8;
typedef __attribute__((ext_vector_type(8))) unsigned short u16x8;

__device__ __forceinline__ unsigned short f2bf(float f) {
  __hip_bfloat16 h = __float2bfloat16(f);
  return __builtin_bit_cast(unsigned short, h);
}
__device__ __forceinline__ float bf2f(unsigned short u) {
  return __builtin_bit_cast(float, ((unsigned int)u) << 16);
}

#define GLL16(gsrc, ldst)                                                              \
  __builtin_amdgcn_global_load_lds((const __attribute__((address_space(1))) void*)(gsrc), \
                                   (__attribute__((address_space(3))) void*)(ldst), 16, 0, 0)

// Row-XOR swizzle for 64B rows (involution), measured 0 conflicts in R5:
// toggle 16B-slot bits [5:4] with row bits [2:1] (byte bits [8:7]).
#define SWZ(x) ((x) ^ ((((x) >> 7) & 3) << 4))

#define MFMA_BF16 __builtin_amdgcn_mfma_f32_16x16x32_bf16

// ---------------- conversion kernels ----------------
__global__ __launch_bounds__(256) void cvt_x_kernel(const float* __restrict__ in,
                                                    unsigned short* __restrict__ out, int n4) {
  int i = blockIdx.x * blockDim.x + threadIdx.x;
  int stride = gridDim.x * blockDim.x;
  for (; i < n4; i += stride) {
    float4 v = reinterpret_cast<const float4*>(in)[i];
    ushort4 o;
    o.x = f2bf(v.x); o.y = f2bf(v.y); o.z = f2bf(v.z); o.w = f2bf(v.w);
    reinterpret_cast<ushort4*>(out)[i] = o;
  }
}

__global__ __launch_bounds__(256) void cvt_T_kernel(const float* __restrict__ in,
                                                    unsigned short* __restrict__ out,
                                                    int R, int C) {
  int idx = blockIdx.x * 256 + threadIdx.x;
  if (idx < R * C) {
    int r = idx / C, c = idx - r * C;
    out[(size_t)c * R + r] = f2bf(in[idx]);
  }
}

// ---------------- 128x256 GEMM, BK=32 dbuf: C[M,N] = A[M,K] * B[N,K]^T ----------------
// 512 threads = 8 waves (2M x 4N), per-wave 64x64 out (acc[4][4] = 64 regs).
// LDS: A 2x8K + B 2x16K = 48 KiB. Per K-tile u:
//   ph1 {read Af m0-1 + Bf all; stage A(u+1); MFMA m0-1}
//   ph2 {read Af m2-3; stage B(u+2); vmcnt(2); MFMA m2-3}
template <bool OUT_BF16>
__global__ __launch_bounds__(512, 4) void gemm2p(const unsigned short* __restrict__ A, int lda,
                                                 const unsigned short* __restrict__ B, int ldb,
                                                 void* __restrict__ Cv, int ldc,
                                                 const float* __restrict__ bias, int N, int K) {
  __shared__ alignas(16) unsigned char lds[49152];  // A: [0,16K) 2x8K; B: [16K,48K) 2x16K
  const int tid = threadIdx.x, lane = tid & 63, wave = tid >> 6;
  const int wm = wave >> 2, wn = wave & 3;
  const int nbn = N >> 8;
  const int nwg = gridDim.x;
  const int b0 = blockIdx.x;
  const int sb = (b0 & 7) * (nwg >> 3) + (b0 >> 3);  // bijective: nwg % 8 == 0
  const int bm = sb / nbn, bn = sb - bm * nbn;
  const int m0 = bm << 7, n0 = bn << 8;
  const int nkt = K >> 5;

  // staging: A tile = 128 rows x 64B = 8192 B (1 GLL16/thread);
  //          B tile = 256 rows x 64B = 16384 B (2 GLL16/thread).
  const int d0 = tid * 16;
  const int r0g = d0 >> 6;
  const int c0 = (SWZ(d0) & 63) >> 1;
  const int d1 = d0 + 8192;
  const int r1g = d1 >> 6;
  const int c1 = (SWZ(d1) & 63) >> 1;

  const int fr = lane & 15, fk = lane >> 4;
  const int fkb = fk * 16;  // 16B k-slot within 64B row

  auto STAGE_A = [&](const unsigned short* __restrict__ S, int ld, int kt, int base) {
    GLL16(S + (size_t)(m0 + r0g) * ld + kt * 32 + c0, &lds[base + wave * 1024]);
  };
  auto STAGE_B = [&](const unsigned short* __restrict__ S, int ld, int kt, int base) {
    auto* lb = &lds[base + wave * 1024];
    GLL16(S + (size_t)(n0 + r0g) * ld + kt * 32 + c0, lb);
    GLL16(S + (size_t)(n0 + r1g) * ld + kt * 32 + c1, lb + 8192);
  };
  auto LDA_ = [&](int abuf, int mi) -> bf16x8 {
    const int e = (wm * 64 + mi * 16 + fr) * 64 + fkb;
    return *reinterpret_cast<const bf16x8*>(&lds[abuf + SWZ(e)]);
  };
  auto LDB_ = [&](int bbuf, int ni) -> bf16x8 {
    const int e = (wn * 64 + ni * 16 + fr) * 64 + fkb;
    return *reinterpret_cast<const bf16x8*>(&lds[bbuf + SWZ(e)]);
  };

  // prologue: A(0) [1 load], B(0) [2], B(1) [2]; vmcnt(2) => A(0),B(0) landed, B(1) in flight
  STAGE_A(A, lda, 0, 0);
  STAGE_B(B, ldb, 0, 16384);
  STAGE_B(B, ldb, (nkt > 1) ? 1 : 0, 16384 + 16384);
  asm volatile("s_waitcnt vmcnt(2)" ::: "memory");
  __builtin_amdgcn_s_barrier();

  f32x4 acc[4][4] = {};
  bf16x8 Af[2], Bf[4];

  for (int u = 0; u < nkt; ++u) {
    const int abuf = (u & 1) * 8192;
    const int anx = ((u + 1) & 1) * 8192;
    const int bbuf = 16384 + (u & 1) * 16384;
    const int kA = (u + 1 < nkt) ? u + 1 : nkt - 1;
    const int kB = (u + 2 < nkt) ? u + 2 : nkt - 1;

    // ---- phase 1: read Af m0-1 + Bf n0-3; stage A(u+1); MFMA (m0-1 x n0-3)
    Af[0] = LDA_(abuf, 0);
    Af[1] = LDA_(abuf, 1);
#pragma unroll
    for (int ni = 0; ni < 4; ++ni) Bf[ni] = LDB_(bbuf, ni);
    STAGE_A(A, lda, kA, anx);
    __builtin_amdgcn_s_barrier();
    asm volatile("s_waitcnt lgkmcnt(0)" ::: "memory");
    __builtin_amdgcn_s_setprio(1);
#pragma unroll
    for (int mi = 0; mi < 2; ++mi)
#pragma unroll
      for (int ni = 0; ni < 4; ++ni)
        acc[mi][ni] = MFMA_BF16(Af[mi], Bf[ni], acc[mi][ni], 0, 0, 0);
    __builtin_amdgcn_s_setprio(0);
    __builtin_amdgcn_s_barrier();

    // ---- phase 2: read Af m2-3; stage B(u+2) into bbuf (B reads certified in ph1); vmcnt(2)
    Af[0] = LDA_(abuf, 2);
    Af[1] = LDA_(abuf, 3);
    STAGE_B(B, ldb, kB, bbuf);
    asm volatile("s_waitcnt vmcnt(2)" ::: "memory");
    __builtin_amdgcn_s_barrier();
    asm volatile("s_waitcnt lgkmcnt(0)" ::: "memory");
    __builtin_amdgcn_s_setprio(1);
#pragma unroll
    for (int mi = 0; mi < 2; ++mi)
#pragma unroll
      for (int ni = 0; ni < 4; ++ni)
        acc[2 + mi][ni] = MFMA_BF16(Af[mi], Bf[ni], acc[2 + mi][ni], 0, 0, 0);
    __builtin_amdgcn_s_setprio(0);
    __builtin_amdgcn_s_barrier();
  }

  // epilogue: C/D layout col = lane&15, row = (lane>>4)*4 + r
  const int er = fk << 2;
#pragma unroll
  for (int mi = 0; mi < 4; ++mi)
#pragma unroll
    for (int ni = 0; ni < 4; ++ni) {
      const int col = n0 + wn * 64 + ni * 16 + fr;
#pragma unroll
      for (int r = 0; r < 4; ++r) {
        const size_t row = (size_t)(m0 + wm * 64 + mi * 16 + er + r);
        if (OUT_BF16)
          ((unsigned short*)Cv)[row * ldc + col] = f2bf(acc[mi][ni][r]);
        else
          ((float*)Cv)[row * ldc + col] = acc[mi][ni][r] + bias[col];
      }
    }
}

// ---------------- windowed attention ----------------
__device__ __forceinline__ int region_of(int wy, int wx, int t) {
  int yr = wy * 8 + (t >> 3);
  int xr = wx * 8 + (t & 7);
  int ry = (yr < 24) ? 0 : ((yr < 28) ? 1 : 2);
  int rx = (xr < 24) ? 0 : ((xr < 28) ? 1 : 2);
  return ry * 3 + rx;
}

__global__ __launch_bounds__(256) void win_attn(const unsigned short* __restrict__ qkv,
                                                const float* __restrict__ bias_table,
                                                unsigned short* __restrict__ out,
                                                int nb16) {
  __shared__ alignas(16) unsigned short vt[4][64][72];
  __shared__ alignas(16) unsigned short pl[4][64][72];
  __shared__ unsigned short bias_sh[225 * 16];

  const int tid = threadIdx.x, lane = tid & 63, wave = tid >> 6;
  const int bid = blockIdx.x;
  const int g = bid / nb16;
  const int bw = bid - g * nb16;
  const int b = bw >> 4, w = bw & 15;
  const int wy = w >> 2, wx = w & 3;
  const int shift = g ? 4 : 0;

  for (int i = tid; i < 225 * 16; i += 256) bias_sh[i] = f2bf(bias_table[i]);
  __syncthreads();

  const int r0 = lane & 15, hi4 = lane >> 4;

  for (int hh = 0; hh < 2; ++hh) {
    const int head = g * 8 + wave * 2 + hh;
    const int qcol = head * 64;

    bf16x8 qf[4][2], kf[4][2];
#pragma unroll
    for (int mi = 0; mi < 4; ++mi) {
      const int t = mi * 16 + r0;
      const int y = (wy * 8 + (t >> 3) + shift) & 31;
      const int x = (wx * 8 + (t & 7) + shift) & 31;
      const size_t base = (size_t)((b << 10) + (y << 5) + x) * 3072 + qcol;
#pragma unroll
      for (int kb = 0; kb < 2; ++kb) {
        const int d = kb * 32 + hi4 * 8;
        qf[mi][kb] = *reinterpret_cast<const bf16x8*>(&qkv[base + d]);
        kf[mi][kb] = *reinterpret_cast<const bf16x8*>(&qkv[base + 1024 + d]);
      }
    }

    {
      const int y = (wy * 8 + (lane >> 3) + shift) & 31;
      const int x = (wx * 8 + (lane & 7) + shift) & 31;
      const unsigned short* vsrc =
          qkv + (size_t)((b << 10) + (y << 5) + x) * 3072 + 2048 + qcol;
#pragma unroll
      for (int d0 = 0; d0 < 8; ++d0) {
        u16x8 vv = *reinterpret_cast<const u16x8*>(&vsrc[d0 * 8]);
#pragma unroll
        for (int jj = 0; jj < 8; ++jj) vt[wave][d0 * 8 + jj][lane] = vv[jj];
      }
    }

    f32x4 s[4][4] = {};
#pragma unroll
    for (int mi = 0; mi < 4; ++mi)
#pragma unroll
      for (int ni = 0; ni < 4; ++ni) {
        s[mi][ni] = MFMA_BF16(qf[mi][0], kf[ni][0], s[mi][ni], 0, 0, 0);
        s[mi][ni] = MFMA_BF16(qf[mi][1], kf[ni][1], s[mi][ni], 0, 0, 0);
      }

    int rj[4];
#pragma unroll
    for (int ni = 0; ni < 4; ++ni) rj[ni] = region_of(wy, wx, ni * 16 + r0);
    float rinv[4][4];
#pragma unroll
    for (int mi = 0; mi < 4; ++mi) {
#pragma unroll
      for (int r = 0; r < 4; ++r) {
        const int it = mi * 16 + hi4 * 4 + r;
        const int iy = it >> 3, ix = it & 7;
        const int ri = region_of(wy, wx, it);
        float vals[4], vmax = -1e30f;
#pragma unroll
        for (int ni = 0; ni < 4; ++ni) {
          const int jt = ni * 16 + r0;
          const int ridx = (iy - (jt >> 3) + 7) * 15 + (ix - (jt & 7) + 7);
          float v = s[mi][ni][r] * 0.125f + bf2f(bias_sh[ridx * 16 + head]);
          if (g && ri != rj[ni]) v = -1e9f;
          vals[ni] = v;
          vmax = fmaxf(vmax, v);
        }
        vmax = fmaxf(vmax, __shfl_xor(vmax, 1));
        vmax = fmaxf(vmax, __shfl_xor(vmax, 2));
        vmax = fmaxf(vmax, __shfl_xor(vmax, 4));
        vmax = fmaxf(vmax, __shfl_xor(vmax, 8));
        float ssum = 0.f;
#pragma unroll
        for (int ni = 0; ni < 4; ++ni) {
          float p = __expf(vals[ni] - vmax);
          ssum += p;
          s[mi][ni][r] = p;
        }
        ssum += __shfl_xor(ssum, 1);
        ssum += __shfl_xor(ssum, 2);
        ssum += __shfl_xor(ssum, 4);
        ssum += __shfl_xor(ssum, 8);
        rinv[mi][r] = 1.0f / ssum;
      }
    }

#pragma unroll
    for (int mi = 0; mi < 4; ++mi)
#pragma unroll
      for (int ni = 0; ni < 4; ++ni)
#pragma unroll
        for (int r = 0; r < 4; ++r)
          pl[wave][mi * 16 + hi4 * 4 + r][ni * 16 + r0] = f2bf(s[mi][ni][r]);

    f32x4 o[4][4] = {};
#pragma unroll
    for (int kb = 0; kb < 2; ++kb) {
      bf16x8 pf[4], vf[4];
#pragma unroll
      for (int mi = 0; mi < 4; ++mi)
        pf[mi] = *reinterpret_cast<const bf16x8*>(&pl[wave][mi * 16 + r0][kb * 32 + hi4 * 8]);
#pragma unroll
      for (int di = 0; di < 4; ++di)
        vf[di] = *reinterpret_cast<const bf16x8*>(&vt[wave][di * 16 + r0][kb * 32 + hi4 * 8]);
#pragma unroll
      for (int mi = 0; mi < 4; ++mi)
#pragma unroll
        for (int di = 0; di < 4; ++di)
          o[mi][di] = MFMA_BF16(pf[mi], vf[di], o[mi][di], 0, 0, 0);
    }

#pragma unroll
    for (int mi = 0; mi < 4; ++mi)
#pragma unroll
      for (int r = 0; r < 4; ++r) {
        const int it = mi * 16 + hi4 * 4 + r;
        const int y = (wy * 8 + (it >> 3) + shift) & 31;
        const int x = (wx * 8 + (it & 7) + shift) & 31;
        unsigned short* op = out + (size_t)((b << 10) + (y << 5) + x) * 3072 + head * 64;
        const float rv = rinv[mi][r];
#pragma unroll
        for (int di = 0; di < 4; ++di) op[di * 16 + r0] = f2bf(o[mi][di][r] * rv);
      }
  }
}

// ---------------- launcher ----------------
extern "C" void kernel_launch(void* const* d_in, const int* in_sizes, int n_in,
                              void* d_out, int out_size, void* d_ws, size_t ws_size,
                              hipStream_t stream) {
  const float* x = (const float*)d_in[0];
  const float* w_qkv = (const float*)d_in[1];
  const float* bias_table = (const float*)d_in[2];
  const float* w_out = (const float*)d_in[3];
  const float* b_out = (const float*)d_in[4];
  float* out = (float*)d_out;

  int S = 1;
  for (; S < 16; S <<= 1) {
    size_t need = 2ull * (2097152ull + 234881024ull / (size_t)S);
    if (need <= ws_size) break;
  }
  const int Mc = 65536 / S;
  const int nb = 64 / S;

  unsigned short* wqt = (unsigned short*)d_ws;
  unsigned short* wot = wqt + (size_t)1572864;
  unsigned short* xb  = wot + (size_t)524288;
  unsigned short* qkv = xb + (size_t)Mc * 512;

  cvt_T_kernel<<<6144, 256, 0, stream>>>(w_qkv, wqt, 512, 3072);
  cvt_T_kernel<<<2048, 256, 0, stream>>>(w_out, wot, 1024, 512);

  for (int c = 0; c < S; ++c) {
    const float* xc = x + (size_t)c * Mc * 512;
    cvt_x_kernel<<<2048, 256, 0, stream>>>(xc, xb, Mc * 128);
    gemm2p<true><<<(Mc >> 7) * 12, 512, 0, stream>>>(xb, 512, wqt, 512, (void*)qkv, 3072,
                                                     nullptr, 3072, 512);
    win_attn<<<2 * nb * 16, 256, 0, stream>>>(qkv, bias_table, qkv, nb * 16);
    gemm2p<false><<<(Mc >> 7) * 2, 512, 0, stream>>>(qkv, 3072, wot, 1024,
                                                     (void*)(out + (size_t)c * Mc * 512), 512,
                                                     b_out, 512, 1024);
  }
}